// Round 1
// baseline (209.905 us; speedup 1.0000x reference)
//
#include <hip/hip_runtime.h>
#include <hip/hip_bf16.h>
#include <cstdint>
#include <cstddef>

#define D_MODEL 1024
#define NUM_HEADS 16
#define DK_DIM 64
#define BATCH 2
#define SEQ 4096
#define MROWS (BATCH*SEQ)
#define NCHUNK 64
#define CHUNK 64

typedef __attribute__((ext_vector_type(4))) float f32x4;
typedef __attribute__((ext_vector_type(8))) short bf16x8;
typedef __attribute__((ext_vector_type(4))) short s16x4;

__device__ __forceinline__ float b2f(short s) {
  union { uint32_t u; float f; } c; c.u = ((uint32_t)(uint16_t)s) << 16; return c.f;
}
__device__ __forceinline__ short f2b(float f) {
  union { float f; uint32_t u; } c; c.f = f;
  uint32_t u = c.u;
  u += 0x7FFFu + ((u >> 16) & 1u);
  return (short)(u >> 16);
}

// ---------------- f32 -> bf16 conversion (vectorized) ----------------
__global__ __launch_bounds__(256) void cvt_f32_bf16(const float* __restrict__ in,
                                                    short* __restrict__ out, int n4) {
  int i = blockIdx.x * 256 + threadIdx.x;
  if (i >= n4) return;
  float4 v = reinterpret_cast<const float4*>(in)[i];
  s16x4 o;
  o.x = f2b(v.x); o.y = f2b(v.y); o.z = f2b(v.z); o.w = f2b(v.w);
  reinterpret_cast<s16x4*>(out)[i] = o;
}

// ---------------- bf16 GEMM: C[m][n] = sum_k A[m][k]*W[n][k] + bias[n] ---------
// A: [M][K] bf16 row-major; W: [N][K] bf16 row-major (i.e. X @ W.T)
// ACT: apply elu(x)+1 ; OUTBF16: store bf16 else f32
template<int ACT, int OUTBF16>
__global__ __launch_bounds__(256) void gemm_bt(
    const short* __restrict__ A, const short* __restrict__ Bw,
    const float* __restrict__ bias, void* __restrict__ Cout,
    int Kdim, int Ndim)
{
  __shared__ short As[128 * 64];
  __shared__ short Bs[128 * 64];
  const int tid = threadIdx.x;
  const int wid = tid >> 6;
  const int lane = tid & 63;
  const int brow = blockIdx.x * 128;
  const int bcol = blockIdx.y * 128;
  const int wr = wid >> 1, wc = wid & 1;

  f32x4 acc[4][4];
#pragma unroll
  for (int i = 0; i < 4; ++i)
#pragma unroll
    for (int j = 0; j < 4; ++j)
#pragma unroll
      for (int t = 0; t < 4; ++t) acc[i][j][t] = 0.f;

  const int srow = lane >> 3;          // row within this wave's 8-row staging group
  const int skel = (lane & 7) * 8;     // bf16 element offset within row (16B granules)

  for (int k0 = 0; k0 < Kdim; k0 += 64) {
    __syncthreads();  // previous compute done before LDS overwrite
#pragma unroll
    for (int iss = 0; iss < 4; ++iss) {
      const int r = iss * 32 + wid * 8;  // wave-uniform base row of this 8-row group
      const short* gA = A + (size_t)(brow + r + srow) * Kdim + k0 + skel;
      const short* gB = Bw + (size_t)(bcol + r + srow) * Kdim + k0 + skel;
      __builtin_amdgcn_global_load_lds((const __attribute__((address_space(1))) void*)gA,
                                       (__attribute__((address_space(3))) void*)(As + r * 64),
                                       16, 0, 0);
      __builtin_amdgcn_global_load_lds((const __attribute__((address_space(1))) void*)gB,
                                       (__attribute__((address_space(3))) void*)(Bs + r * 64),
                                       16, 0, 0);
    }
    __syncthreads();  // drains vmcnt, loads visible
#pragma unroll
    for (int kk = 0; kk < 2; ++kk) {
      const int kof = kk * 32 + (lane >> 4) * 8;
      bf16x8 af[4], bfr[4];
#pragma unroll
      for (int i = 0; i < 4; ++i)
        af[i] = *reinterpret_cast<const bf16x8*>(&As[(wr * 64 + i * 16 + (lane & 15)) * 64 + kof]);
#pragma unroll
      for (int j = 0; j < 4; ++j)
        bfr[j] = *reinterpret_cast<const bf16x8*>(&Bs[(wc * 64 + j * 16 + (lane & 15)) * 64 + kof]);
#pragma unroll
      for (int i = 0; i < 4; ++i)
#pragma unroll
        for (int j = 0; j < 4; ++j)
          acc[i][j] = __builtin_amdgcn_mfma_f32_16x16x32_bf16(af[i], bfr[j], acc[i][j], 0, 0, 0);
    }
  }

  // epilogue: C/D layout col=lane&15, row=(lane>>4)*4 + t  (m89/m91 verified)
  const int rsub = (lane >> 4) * 4;
  const int csub = lane & 15;
#pragma unroll
  for (int j = 0; j < 4; ++j) {
    const int col = bcol + wc * 64 + j * 16 + csub;
    const float bv = bias[col];
#pragma unroll
    for (int i = 0; i < 4; ++i) {
#pragma unroll
      for (int t = 0; t < 4; ++t) {
        const int row = brow + wr * 64 + i * 16 + rsub + t;
        float v = acc[i][j][t] + bv;
        if (ACT) v = (v > 0.f) ? (v + 1.f) : __expf(v);
        if (OUTBF16) ((short*)Cout)[(size_t)row * Ndim + col] = f2b(v);
        else ((float*)Cout)[(size_t)row * Ndim + col] = v;
      }
    }
  }
}

// ---------------- pass A: per-chunk partial sums of kf, vf ----------------
// grid: 512 blocks x 256 thr; each wave handles one (b,h,c); lane = d
__global__ __launch_bounds__(256) void chunk_sums(
    const short* __restrict__ kf, const short* __restrict__ vf,
    float* __restrict__ ck, float* __restrict__ cv)
{
  const int gw = blockIdx.x * 4 + (threadIdx.x >> 6);  // 0..2047
  const int lane = threadIdx.x & 63;
  const int c = gw & (NCHUNK - 1);
  const int h = (gw >> 6) & (NUM_HEADS - 1);
  const int b = gw >> 10;
  float sk = 0.f, sv = 0.f;
  for (int p = 0; p < CHUNK; ++p) {
    const int l = c * CHUNK + p;
    const size_t off = ((size_t)(b * SEQ + l) * NUM_HEADS + h) * DK_DIM + lane;
    sk += b2f(kf[off]);
    sv += b2f(vf[off]);
  }
  const size_t o = ((size_t)((b * NUM_HEADS + h) * NCHUNK + c)) * DK_DIM + lane;
  ck[o] = sk;
  cv[o] = sv;
}

// ---------------- pass B: exclusive scan over chunks (in place) + totals ------
// grid: 32 blocks (b*h) x 64 threads (d)
__global__ __launch_bounds__(64) void chunk_scan(
    float* __restrict__ ck, float* __restrict__ cv, float* __restrict__ ksum)
{
  const int bh = blockIdx.x;
  const int d = threadIdx.x;
  float rk = 0.f, rv = 0.f;
  for (int c = 0; c < NCHUNK; ++c) {
    const size_t o = ((size_t)(bh * NCHUNK + c)) * DK_DIM + d;
    const float tk = ck[o], tv = cv[o];
    ck[o] = rk; cv[o] = rv;  // exclusive prefix
    rk += tk; rv += tv;
  }
  ksum[bh * DK_DIM + d] = rk;  // full-sequence k sum
}

// ---------------- pass C: local cumsum + context ----------------
__global__ __launch_bounds__(256) void scan_ctx(
    const short* __restrict__ qf, const short* __restrict__ kf,
    const short* __restrict__ vf,
    const float* __restrict__ ck, const float* __restrict__ cv,
    const float* __restrict__ ksum, short* __restrict__ ctx)
{
  const int gw = blockIdx.x * 4 + (threadIdx.x >> 6);
  const int lane = threadIdx.x & 63;
  const int c = gw & (NCHUNK - 1);
  const int h = (gw >> 6) & (NUM_HEADS - 1);
  const int b = gw >> 10;
  const int bh = b * NUM_HEADS + h;
  float krun = ck[((size_t)(bh * NCHUNK + c)) * DK_DIM + lane];
  float vrun = cv[((size_t)(bh * NCHUNK + c)) * DK_DIM + lane];
  const float kst = ksum[bh * DK_DIM + lane];
  for (int p = 0; p < CHUNK; ++p) {
    const int l = c * CHUNK + p;
    const size_t off = ((size_t)(b * SEQ + l) * NUM_HEADS + h) * DK_DIM + lane;
    const float q = b2f(qf[off]);
    krun += b2f(kf[off]);
    vrun += b2f(vf[off]);
    float s1 = q * krun;   // -> dot(qf, k_cum)
    float s2 = q * kst;    // -> dot(qf, k_sum_total)
#pragma unroll
    for (int m = 1; m < 64; m <<= 1) {
      s1 += __shfl_xor(s1, m, 64);
      s2 += __shfl_xor(s2, m, 64);
    }
    const float z = 1.0f / (s2 + 1e-6f);
    ctx[off] = f2b(s1 * vrun * z);
  }
}

// ---------------- launch ----------------
extern "C" void kernel_launch(void* const* d_in, const int* in_sizes, int n_in,
                              void* d_out, int out_size, void* d_ws, size_t ws_size,
                              hipStream_t stream) {
  const float* q  = (const float*)d_in[0];
  const float* k  = (const float*)d_in[1];
  const float* v  = (const float*)d_in[2];
  const float* Wq = (const float*)d_in[3];
  const float* bq = (const float*)d_in[4];
  const float* Wk = (const float*)d_in[5];
  const float* bk = (const float*)d_in[6];
  const float* Wv = (const float*)d_in[7];
  const float* bv = (const float*)d_in[8];
  const float* Wo = (const float*)d_in[9];
  const float* bo = (const float*)d_in[10];
  float* out = (float*)d_out;

  uint8_t* p = (uint8_t*)d_ws;
  auto alloc = [&](size_t bytes) { uint8_t* r = p; p += bytes; return r; };
  short* inb = (short*)alloc((size_t)MROWS * D_MODEL * 2);   // reused: q,k,v bf16 then ctx
  short* qf  = (short*)alloc((size_t)MROWS * D_MODEL * 2);
  short* kf  = (short*)alloc((size_t)MROWS * D_MODEL * 2);
  short* vf  = (short*)alloc((size_t)MROWS * D_MODEL * 2);
  short* Wqb = (short*)alloc((size_t)D_MODEL * D_MODEL * 2);
  short* Wkb = (short*)alloc((size_t)D_MODEL * D_MODEL * 2);
  short* Wvb = (short*)alloc((size_t)D_MODEL * D_MODEL * 2);
  short* Wob = (short*)alloc((size_t)D_MODEL * D_MODEL * 2);
  float* ck   = (float*)alloc((size_t)BATCH * NUM_HEADS * NCHUNK * DK_DIM * 4);
  float* cv   = (float*)alloc((size_t)BATCH * NUM_HEADS * NCHUNK * DK_DIM * 4);
  float* ksum = (float*)alloc((size_t)BATCH * NUM_HEADS * DK_DIM * 4);
  short* ctx = inb;  // safe: inb free after the 3rd projection GEMM (stream-ordered)

  const int n4in = MROWS * D_MODEL / 4;      // 2,097,152
  const int n4w  = D_MODEL * D_MODEL / 4;    // 262,144
  const dim3 ggrid(MROWS / 128, D_MODEL / 128);  // (64, 8)

  // weights -> bf16
  cvt_f32_bf16<<<n4w / 256, 256, 0, stream>>>(Wq, Wqb, n4w);
  cvt_f32_bf16<<<n4w / 256, 256, 0, stream>>>(Wk, Wkb, n4w);
  cvt_f32_bf16<<<n4w / 256, 256, 0, stream>>>(Wv, Wvb, n4w);
  cvt_f32_bf16<<<n4w / 256, 256, 0, stream>>>(Wo, Wob, n4w);

  // q projection (+elu+1)
  cvt_f32_bf16<<<n4in / 256, 256, 0, stream>>>(q, inb, n4in);
  gemm_bt<1, 1><<<ggrid, 256, 0, stream>>>(inb, Wqb, bq, qf, D_MODEL, D_MODEL);
  // k projection (+elu+1)
  cvt_f32_bf16<<<n4in / 256, 256, 0, stream>>>(k, inb, n4in);
  gemm_bt<1, 1><<<ggrid, 256, 0, stream>>>(inb, Wkb, bk, kf, D_MODEL, D_MODEL);
  // v projection
  cvt_f32_bf16<<<n4in / 256, 256, 0, stream>>>(v, inb, n4in);
  gemm_bt<0, 1><<<ggrid, 256, 0, stream>>>(inb, Wvb, bv, vf, D_MODEL, D_MODEL);

  // scan
  chunk_sums<<<512, 256, 0, stream>>>(kf, vf, ck, cv);
  chunk_scan<<<32, 64, 0, stream>>>(ck, cv, ksum);
  scan_ctx<<<512, 256, 0, stream>>>(qf, kf, vf, ck, cv, ksum, ctx);

  // output projection (f32 out)
  gemm_bt<0, 0><<<ggrid, 256, 0, stream>>>(ctx, Wob, bo, out, D_MODEL, D_MODEL);
}

// Round 2
// 187.649 us; speedup vs baseline: 1.1186x; 1.1186x over previous
//
#include <hip/hip_runtime.h>
#include <hip/hip_bf16.h>
#include <cstdint>
#include <cstddef>

#define D_MODEL 1024
#define NUM_HEADS 16
#define DK_DIM 64
#define BATCH 2
#define SEQ 4096
#define MROWS (BATCH*SEQ)
#define NCHUNK 128
#define CHUNK 32

typedef __attribute__((ext_vector_type(4))) float f32x4;
typedef __attribute__((ext_vector_type(2))) float f32x2;
typedef __attribute__((ext_vector_type(8))) short bf16x8;
typedef __attribute__((ext_vector_type(4))) short s16x4;

__device__ __forceinline__ float b2f(short s) {
  union { uint32_t u; float f; } c; c.u = ((uint32_t)(uint16_t)s) << 16; return c.f;
}
__device__ __forceinline__ short f2b(float f) {
  union { float f; uint32_t u; } c; c.f = f;
  uint32_t u = c.u;
  u += 0x7FFFu + ((u >> 16) & 1u);
  return (short)(u >> 16);
}
__device__ __forceinline__ f32x4 b4_to_f4(s16x4 s) {
  f32x4 r;
  r.x = b2f(s.x); r.y = b2f(s.y); r.z = b2f(s.z); r.w = b2f(s.w);
  return r;
}

// ---------------- f32 -> bf16 conversion (vectorized) ----------------
__global__ __launch_bounds__(256) void cvt_f32_bf16(const float* __restrict__ in,
                                                    short* __restrict__ out, int n4) {
  int i = blockIdx.x * 256 + threadIdx.x;
  if (i >= n4) return;
  float4 v = reinterpret_cast<const float4*>(in)[i];
  s16x4 o;
  o.x = f2b(v.x); o.y = f2b(v.y); o.z = f2b(v.z); o.w = f2b(v.w);
  reinterpret_cast<s16x4*>(out)[i] = o;
}

// ---------------- bf16 GEMM: C[m][n] = sum_k A[m][k]*W[n][k] + bias[n] ---------
template<int ACT, int OUTBF16>
__global__ __launch_bounds__(256) void gemm_bt(
    const short* __restrict__ A, const short* __restrict__ Bw,
    const float* __restrict__ bias, void* __restrict__ Cout,
    int Kdim, int Ndim)
{
  __shared__ short As[128 * 64];
  __shared__ short Bs[128 * 64];
  const int tid = threadIdx.x;
  const int wid = tid >> 6;
  const int lane = tid & 63;
  const int brow = blockIdx.x * 128;
  const int bcol = blockIdx.y * 128;
  const int wr = wid >> 1, wc = wid & 1;

  f32x4 acc[4][4];
#pragma unroll
  for (int i = 0; i < 4; ++i)
#pragma unroll
    for (int j = 0; j < 4; ++j)
#pragma unroll
      for (int t = 0; t < 4; ++t) acc[i][j][t] = 0.f;

  const int srow = lane >> 3;
  const int skel = (lane & 7) * 8;

  for (int k0 = 0; k0 < Kdim; k0 += 64) {
    __syncthreads();
#pragma unroll
    for (int iss = 0; iss < 4; ++iss) {
      const int r = iss * 32 + wid * 8;
      const short* gA = A + (size_t)(brow + r + srow) * Kdim + k0 + skel;
      const short* gB = Bw + (size_t)(bcol + r + srow) * Kdim + k0 + skel;
      __builtin_amdgcn_global_load_lds((const __attribute__((address_space(1))) void*)gA,
                                       (__attribute__((address_space(3))) void*)(As + r * 64),
                                       16, 0, 0);
      __builtin_amdgcn_global_load_lds((const __attribute__((address_space(1))) void*)gB,
                                       (__attribute__((address_space(3))) void*)(Bs + r * 64),
                                       16, 0, 0);
    }
    __syncthreads();
#pragma unroll
    for (int kk = 0; kk < 2; ++kk) {
      const int kof = kk * 32 + (lane >> 4) * 8;
      bf16x8 af[4], bfr[4];
#pragma unroll
      for (int i = 0; i < 4; ++i)
        af[i] = *reinterpret_cast<const bf16x8*>(&As[(wr * 64 + i * 16 + (lane & 15)) * 64 + kof]);
#pragma unroll
      for (int j = 0; j < 4; ++j)
        bfr[j] = *reinterpret_cast<const bf16x8*>(&Bs[(wc * 64 + j * 16 + (lane & 15)) * 64 + kof]);
#pragma unroll
      for (int i = 0; i < 4; ++i)
#pragma unroll
        for (int j = 0; j < 4; ++j)
          acc[i][j] = __builtin_amdgcn_mfma_f32_16x16x32_bf16(af[i], bfr[j], acc[i][j], 0, 0, 0);
    }
  }

  const int rsub = (lane >> 4) * 4;
  const int csub = lane & 15;
#pragma unroll
  for (int j = 0; j < 4; ++j) {
    const int col = bcol + wc * 64 + j * 16 + csub;
    const float bv = bias[col];
#pragma unroll
    for (int i = 0; i < 4; ++i) {
#pragma unroll
      for (int t = 0; t < 4; ++t) {
        const int row = brow + wr * 64 + i * 16 + rsub + t;
        float v = acc[i][j][t] + bv;
        if (ACT) v = (v > 0.f) ? (v + 1.f) : __expf(v);
        if (OUTBF16) ((short*)Cout)[(size_t)row * Ndim + col] = f2b(v);
        else ((float*)Cout)[(size_t)row * Ndim + col] = v;
      }
    }
  }
}

// ---------------- pass A: per-chunk partial sums of kf, vf ----------------
// 4096 waves, one per (b,h,c32). lane: half=lane>>5 (pos parity), dpair=(lane&31)*2
__global__ __launch_bounds__(256) void chunk_sums(
    const short* __restrict__ kf, const short* __restrict__ vf,
    float* __restrict__ ck, float* __restrict__ cv)
{
  const int gw = blockIdx.x * 4 + (threadIdx.x >> 6);  // 0..4095
  const int lane = threadIdx.x & 63;
  const int c = gw & (NCHUNK - 1);
  const int h = (gw >> 7) & (NUM_HEADS - 1);
  const int b = gw >> 11;
  const int half = lane >> 5;
  const int dpair = (lane & 31) * 2;
  const size_t base = ((size_t)(b * SEQ + c * CHUNK) * NUM_HEADS + h) * DK_DIM + dpair;

  float skx = 0.f, sky = 0.f, svx = 0.f, svy = 0.f;
#pragma unroll
  for (int i = 0; i < CHUNK / 2; ++i) {
    const size_t off = base + (size_t)(2 * i + half) * D_MODEL;
    uint32_t ku = *reinterpret_cast<const uint32_t*>(&kf[off]);
    uint32_t vu = *reinterpret_cast<const uint32_t*>(&vf[off]);
    skx += b2f((short)(ku & 0xffff)); sky += b2f((short)(ku >> 16));
    svx += b2f((short)(vu & 0xffff)); svy += b2f((short)(vu >> 16));
  }
  // combine even/odd position halves
  skx += __shfl_xor(skx, 32, 64); sky += __shfl_xor(sky, 32, 64);
  svx += __shfl_xor(svx, 32, 64); svy += __shfl_xor(svy, 32, 64);
  if (half == 0) {
    const size_t o = ((size_t)((b * NUM_HEADS + h) * NCHUNK + c)) * DK_DIM + dpair;
    f32x2 a; a.x = skx; a.y = sky;
    f32x2 bb; bb.x = svx; bb.y = svy;
    *reinterpret_cast<f32x2*>(&ck[o]) = a;
    *reinterpret_cast<f32x2*>(&cv[o]) = bb;
  }
}

// ---------------- pass B: exclusive scan over chunks (in place) + totals ------
__global__ __launch_bounds__(64) void chunk_scan(
    float* __restrict__ ck, float* __restrict__ cv, float* __restrict__ ksum)
{
  const int bh = blockIdx.x;
  const int d = threadIdx.x;
  float rk = 0.f, rv = 0.f;
#pragma unroll 8
  for (int c = 0; c < NCHUNK; ++c) {
    const size_t o = ((size_t)(bh * NCHUNK + c)) * DK_DIM + d;
    const float tk = ck[o], tv = cv[o];
    ck[o] = rk; cv[o] = rv;
    rk += tk; rv += tv;
  }
  ksum[bh * DK_DIM + d] = rk;
}

// ---------------- pass C: local cumsum + context ----------------
// 4096 waves, one per (b,h,c32). lane = pg*16 + dg ; lane owns d = dg*4..dg*4+3
// batches of 4 positions: pg selects which position in the batch this lane reduces.
__global__ __launch_bounds__(256) void scan_ctx(
    const short* __restrict__ qf, const short* __restrict__ kf,
    const short* __restrict__ vf,
    const float* __restrict__ ck, const float* __restrict__ cv,
    const float* __restrict__ ksum, short* __restrict__ ctx)
{
  const int gw = blockIdx.x * 4 + (threadIdx.x >> 6);
  const int lane = threadIdx.x & 63;
  const int pg = lane >> 4;          // 0..3  position within batch
  const int dg = lane & 15;          // 0..15 d-group (4 elems)
  const int c = gw & (NCHUNK - 1);
  const int h = (gw >> 7) & (NUM_HEADS - 1);
  const int b = gw >> 11;
  const int bh = b * NUM_HEADS + h;
  const int d4 = dg * 4;

  // running prefix for this lane's 4 d-elements (same across pg groups)
  f32x4 krun = *reinterpret_cast<const f32x4*>(
      &ck[((size_t)(bh * NCHUNK + c)) * DK_DIM + d4]);
  f32x4 vrun = *reinterpret_cast<const f32x4*>(
      &cv[((size_t)(bh * NCHUNK + c)) * DK_DIM + d4]);
  const f32x4 kst = *reinterpret_cast<const f32x4*>(&ksum[bh * DK_DIM + d4]);

  const size_t base = ((size_t)(b * SEQ + c * CHUNK) * NUM_HEADS + h) * DK_DIM + d4;

  for (int p0 = 0; p0 < CHUNK; p0 += 4) {
    // q for this lane's position (p0+pg)
    const size_t qoff = base + (size_t)(p0 + pg) * D_MODEL;
    const f32x4 q4 = b4_to_f4(*reinterpret_cast<const s16x4*>(&qf[qoff]));
    f32x4 sk, sv;
#pragma unroll
    for (int i = 0; i < 4; ++i) {
      const size_t off = base + (size_t)(p0 + i) * D_MODEL;
      krun += b4_to_f4(*reinterpret_cast<const s16x4*>(&kf[off]));
      vrun += b4_to_f4(*reinterpret_cast<const s16x4*>(&vf[off]));
      if (i == pg) { sk = krun; sv = vrun; }
    }
    float s1 = q4.x * sk.x + q4.y * sk.y + q4.z * sk.z + q4.w * sk.w;
    float s2 = q4.x * kst.x + q4.y * kst.y + q4.z * kst.z + q4.w * kst.w;
#pragma unroll
    for (int m = 1; m < 16; m <<= 1) {
      s1 += __shfl_xor(s1, m, 64);
      s2 += __shfl_xor(s2, m, 64);
    }
    const float g = s1 / (s2 + 1e-6f);
    s16x4 o;
    o.x = f2b(g * sv.x); o.y = f2b(g * sv.y);
    o.z = f2b(g * sv.z); o.w = f2b(g * sv.w);
    *reinterpret_cast<s16x4*>(&ctx[qoff]) = o;
  }
}

// ---------------- launch ----------------
extern "C" void kernel_launch(void* const* d_in, const int* in_sizes, int n_in,
                              void* d_out, int out_size, void* d_ws, size_t ws_size,
                              hipStream_t stream) {
  const float* q  = (const float*)d_in[0];
  const float* k  = (const float*)d_in[1];
  const float* v  = (const float*)d_in[2];
  const float* Wq = (const float*)d_in[3];
  const float* bq = (const float*)d_in[4];
  const float* Wk = (const float*)d_in[5];
  const float* bk = (const float*)d_in[6];
  const float* Wv = (const float*)d_in[7];
  const float* bv = (const float*)d_in[8];
  const float* Wo = (const float*)d_in[9];
  const float* bo = (const float*)d_in[10];
  float* out = (float*)d_out;

  uint8_t* p = (uint8_t*)d_ws;
  auto alloc = [&](size_t bytes) { uint8_t* r = p; p += bytes; return r; };
  short* inb = (short*)alloc((size_t)MROWS * D_MODEL * 2);
  short* qf  = (short*)alloc((size_t)MROWS * D_MODEL * 2);
  short* kf  = (short*)alloc((size_t)MROWS * D_MODEL * 2);
  short* vf  = (short*)alloc((size_t)MROWS * D_MODEL * 2);
  short* Wqb = (short*)alloc((size_t)D_MODEL * D_MODEL * 2);
  short* Wkb = (short*)alloc((size_t)D_MODEL * D_MODEL * 2);
  short* Wvb = (short*)alloc((size_t)D_MODEL * D_MODEL * 2);
  short* Wob = (short*)alloc((size_t)D_MODEL * D_MODEL * 2);
  float* ck   = (float*)alloc((size_t)BATCH * NUM_HEADS * NCHUNK * DK_DIM * 4);
  float* cv   = (float*)alloc((size_t)BATCH * NUM_HEADS * NCHUNK * DK_DIM * 4);
  float* ksum = (float*)alloc((size_t)BATCH * NUM_HEADS * DK_DIM * 4);
  short* ctx = inb;

  const int n4in = MROWS * D_MODEL / 4;
  const int n4w  = D_MODEL * D_MODEL / 4;
  const dim3 ggrid(MROWS / 128, D_MODEL / 128);

  cvt_f32_bf16<<<n4w / 256, 256, 0, stream>>>(Wq, Wqb, n4w);
  cvt_f32_bf16<<<n4w / 256, 256, 0, stream>>>(Wk, Wkb, n4w);
  cvt_f32_bf16<<<n4w / 256, 256, 0, stream>>>(Wv, Wvb, n4w);
  cvt_f32_bf16<<<n4w / 256, 256, 0, stream>>>(Wo, Wob, n4w);

  cvt_f32_bf16<<<n4in / 256, 256, 0, stream>>>(q, inb, n4in);
  gemm_bt<1, 1><<<ggrid, 256, 0, stream>>>(inb, Wqb, bq, qf, D_MODEL, D_MODEL);
  cvt_f32_bf16<<<n4in / 256, 256, 0, stream>>>(k, inb, n4in);
  gemm_bt<1, 1><<<ggrid, 256, 0, stream>>>(inb, Wkb, bk, kf, D_MODEL, D_MODEL);
  cvt_f32_bf16<<<n4in / 256, 256, 0, stream>>>(v, inb, n4in);
  gemm_bt<0, 1><<<ggrid, 256, 0, stream>>>(inb, Wvb, bv, vf, D_MODEL, D_MODEL);

  chunk_sums<<<BATCH * NUM_HEADS * NCHUNK / 4, 256, 0, stream>>>(kf, vf, ck, cv);
  chunk_scan<<<BATCH * NUM_HEADS, 64, 0, stream>>>(ck, cv, ksum);
  scan_ctx<<<BATCH * NUM_HEADS * NCHUNK / 4, 256, 0, stream>>>(qf, kf, vf, ck, cv, ksum, ctx);

  gemm_bt<0, 0><<<ggrid, 256, 0, stream>>>(ctx, Wob, bo, out, D_MODEL, D_MODEL);
}

// Round 3
// 154.590 us; speedup vs baseline: 1.3578x; 1.2139x over previous
//
#include <hip/hip_runtime.h>
#include <hip/hip_bf16.h>
#include <cstdint>
#include <cstddef>

#define D_MODEL 1024
#define NUM_HEADS 16
#define DK_DIM 64
#define BATCH 2
#define SEQ 4096
#define MROWS (BATCH*SEQ)
#define NCHUNK 128
#define CHUNK 32

// ---- 8-wave deep-pipelined GEMM geometry ----
#define BM 256
#define BN 128
#define BK 64
#define NSLOT 3
#define SLOT_SH (BM*BK + BN*BK)       // shorts per LDS slot (24576)
#define KTILES (D_MODEL/BK)           // 16

typedef __attribute__((ext_vector_type(4))) float f32x4;
typedef __attribute__((ext_vector_type(2))) float f32x2;
typedef __attribute__((ext_vector_type(8))) short bf16x8;
typedef __attribute__((ext_vector_type(4))) short s16x4;

__device__ __forceinline__ float b2f(short s) {
  union { uint32_t u; float f; } c; c.u = ((uint32_t)(uint16_t)s) << 16; return c.f;
}
__device__ __forceinline__ short f2b(float f) {
  union { float f; uint32_t u; } c; c.f = f;
  uint32_t u = c.u;
  u += 0x7FFFu + ((u >> 16) & 1u);
  return (short)(u >> 16);
}
__device__ __forceinline__ f32x4 b4_to_f4(s16x4 s) {
  f32x4 r;
  r.x = b2f(s.x); r.y = b2f(s.y); r.z = b2f(s.z); r.w = b2f(s.w);
  return r;
}

// ---------------- f32 -> bf16 conversion (vectorized) ----------------
__global__ __launch_bounds__(256) void cvt_f32_bf16(const float* __restrict__ in,
                                                    short* __restrict__ out, int n4) {
  int i = blockIdx.x * 256 + threadIdx.x;
  if (i >= n4) return;
  float4 v = reinterpret_cast<const float4*>(in)[i];
  s16x4 o;
  o.x = f2b(v.x); o.y = f2b(v.y); o.z = f2b(v.z); o.w = f2b(v.w);
  reinterpret_cast<s16x4*>(out)[i] = o;
}

// ---- 4 weight tensors in one launch; dst regions contiguous ----
__global__ __launch_bounds__(256) void cvt_w4(
    const float* __restrict__ s0, const float* __restrict__ s1,
    const float* __restrict__ s2, const float* __restrict__ s3,
    short* __restrict__ dst) {
  const int y = blockIdx.y;
  const float* s = (y == 0) ? s0 : (y == 1) ? s1 : (y == 2) ? s2 : s3;
  const int i = blockIdx.x * 256 + threadIdx.x;          // < 262144
  float4 v = reinterpret_cast<const float4*>(s)[i];
  s16x4 o;
  o.x = f2b(v.x); o.y = f2b(v.y); o.z = f2b(v.z); o.w = f2b(v.w);
  reinterpret_cast<s16x4*>(dst)[(size_t)y * (D_MODEL * D_MODEL / 4) + i] = o;
}

// ---------------- deep-pipelined bf16 GEMM: C = A @ W.T + bias ----------------
// A: [M][1024] bf16 row-major; W: [N][1024] bf16 row-major.
// 512 thr = 8 waves (4M x 2N), per-wave 64x64 out; BM=256 BN=128 BK=64.
// 3-slot rotating LDS (144KB dynamic), counted vmcnt(6), T2 swizzle, T5 setprio.
template<int OUTBF16>
__global__ __launch_bounds__(512, 2) void gemm8(
    const short* __restrict__ A, const short* __restrict__ Bw,
    const float* __restrict__ bias, void* __restrict__ Cout, int act)
{
  extern __shared__ __align__(16) short lds[];
  const int tid = threadIdx.x;
  const int wid = tid >> 6;
  const int lane = tid & 63;
  const int brow = blockIdx.x * BM;
  const int bcol = blockIdx.y * BN;
  const int wr = wid >> 1, wc = wid & 1;

  f32x4 acc[4][4];
#pragma unroll
  for (int i = 0; i < 4; ++i)
#pragma unroll
    for (int j = 0; j < 4; ++j)
#pragma unroll
      for (int t = 0; t < 4; ++t) acc[i][j][t] = 0.f;

  // staging: dest LDS linear (gload_lds writes base+lane*16); source global
  // granule pre-swizzled by (srow) so that read-side XOR recovers it (rule #21).
  const int srow = lane >> 3;                 // dest row within 8-row wave chunk
  const int sgel = ((lane & 7) ^ srow) * 8;   // pre-swizzled source granule (elems)

  auto stage = [&](int t) {
    short* sA = lds + (t % NSLOT) * SLOT_SH;
    short* sB = sA + BM * BK;
    const int k0 = t * BK;
#pragma unroll
    for (int i = 0; i < 4; ++i) {             // A: 256 rows, 4 rounds of 64
      const int r = i * 64 + wid * 8;
      const short* g = A + (size_t)(brow + r + srow) * D_MODEL + k0 + sgel;
      __builtin_amdgcn_global_load_lds((const __attribute__((address_space(1))) void*)g,
          (__attribute__((address_space(3))) void*)(sA + r * BK), 16, 0, 0);
    }
#pragma unroll
    for (int i = 0; i < 2; ++i) {             // B: 128 rows, 2 rounds of 64
      const int r = i * 64 + wid * 8;
      const short* g = Bw + (size_t)(bcol + r + srow) * D_MODEL + k0 + sgel;
      __builtin_amdgcn_global_load_lds((const __attribute__((address_space(1))) void*)g,
          (__attribute__((address_space(3))) void*)(sB + r * BK), 16, 0, 0);
    }
  };

  stage(0);
  stage(1);   // 12 loads in flight

  const int lane15 = lane & 15;
  const int swz = (lane & 7) << 4;            // read-side XOR (row&7 == lane&7)
  const int kq = (lane >> 4) * 16;            // byte offset of lane's 8-elem k-group

  for (int t = 0; t < KTILES; ++t) {
    // gate: tile t's 6 loads done (t+1's 6 may stay in flight) — T4: never 0 mid-loop
    if (t == KTILES - 1) { asm volatile("s_waitcnt vmcnt(0)" ::: "memory"); }
    else                 { asm volatile("s_waitcnt vmcnt(6)" ::: "memory"); }
    __builtin_amdgcn_s_barrier();
    __builtin_amdgcn_sched_barrier(0);
    // safe: slot (t+2)%3 was last READ at tile t-1; all waves' reads drained
    // before barrier above; writes land only after issue (post-barrier).
    if (t + 2 < KTILES) stage(t + 2);

    const char* sAb = (const char*)(lds + (t % NSLOT) * SLOT_SH);
    const char* sBb = sAb + BM * BK * 2;

    auto rdA = [&](int mi, int ks) -> bf16x8 {
      const int row = wr * 64 + mi * 16 + lane15;
      const int off = row * 128 + (((ks * 64 + kq)) ^ swz);
      return *reinterpret_cast<const bf16x8*>(sAb + off);
    };
    auto rdB = [&](int nj, int ks) -> bf16x8 {
      const int row = wc * 64 + nj * 16 + lane15;
      const int off = row * 128 + (((ks * 64 + kq)) ^ swz);
      return *reinterpret_cast<const bf16x8*>(sBb + off);
    };

    bf16x8 Af[2][2], Bf[2][2][2];   // Af[m2][ks]; Bf[nh][j2][ks]

    // ph0: quadrant (m-half0, n-half0)
#pragma unroll
    for (int m2 = 0; m2 < 2; ++m2)
#pragma unroll
      for (int ks = 0; ks < 2; ++ks) Af[m2][ks] = rdA(m2, ks);
#pragma unroll
    for (int j2 = 0; j2 < 2; ++j2)
#pragma unroll
      for (int ks = 0; ks < 2; ++ks) Bf[0][j2][ks] = rdB(j2, ks);
    __builtin_amdgcn_s_setprio(1);
#pragma unroll
    for (int m2 = 0; m2 < 2; ++m2)
#pragma unroll
      for (int j2 = 0; j2 < 2; ++j2)
#pragma unroll
        for (int ks = 0; ks < 2; ++ks)
          acc[m2][j2] = __builtin_amdgcn_mfma_f32_16x16x32_bf16(Af[m2][ks], Bf[0][j2][ks], acc[m2][j2], 0, 0, 0);
    __builtin_amdgcn_s_setprio(0);
    __builtin_amdgcn_sched_barrier(0);

    // ph1: (m-half0, n-half1) — read B half1, reuse A half0
#pragma unroll
    for (int j2 = 0; j2 < 2; ++j2)
#pragma unroll
      for (int ks = 0; ks < 2; ++ks) Bf[1][j2][ks] = rdB(2 + j2, ks);
    __builtin_amdgcn_s_setprio(1);
#pragma unroll
    for (int m2 = 0; m2 < 2; ++m2)
#pragma unroll
      for (int j2 = 0; j2 < 2; ++j2)
#pragma unroll
        for (int ks = 0; ks < 2; ++ks)
          acc[m2][2 + j2] = __builtin_amdgcn_mfma_f32_16x16x32_bf16(Af[m2][ks], Bf[1][j2][ks], acc[m2][2 + j2], 0, 0, 0);
    __builtin_amdgcn_s_setprio(0);
    __builtin_amdgcn_sched_barrier(0);

    // ph2: (m-half1, n-half1) — read A half1, reuse B half1
#pragma unroll
    for (int m2 = 0; m2 < 2; ++m2)
#pragma unroll
      for (int ks = 0; ks < 2; ++ks) Af[m2][ks] = rdA(2 + m2, ks);
    __builtin_amdgcn_s_setprio(1);
#pragma unroll
    for (int m2 = 0; m2 < 2; ++m2)
#pragma unroll
      for (int j2 = 0; j2 < 2; ++j2)
#pragma unroll
        for (int ks = 0; ks < 2; ++ks)
          acc[2 + m2][2 + j2] = __builtin_amdgcn_mfma_f32_16x16x32_bf16(Af[m2][ks], Bf[1][j2][ks], acc[2 + m2][2 + j2], 0, 0, 0);
    __builtin_amdgcn_s_setprio(0);
    __builtin_amdgcn_sched_barrier(0);

    // ph3: (m-half1, n-half0) — no reads
    __builtin_amdgcn_s_setprio(1);
#pragma unroll
    for (int m2 = 0; m2 < 2; ++m2)
#pragma unroll
      for (int j2 = 0; j2 < 2; ++j2)
#pragma unroll
        for (int ks = 0; ks < 2; ++ks)
          acc[2 + m2][j2] = __builtin_amdgcn_mfma_f32_16x16x32_bf16(Af[m2][ks], Bf[0][j2][ks], acc[2 + m2][j2], 0, 0, 0);
    __builtin_amdgcn_s_setprio(0);
    __builtin_amdgcn_sched_barrier(0);
  }

  // epilogue: C/D layout col=lane&15, row=(lane>>4)*4 + t
  const int rsub = (lane >> 4) * 4;
#pragma unroll
  for (int nj = 0; nj < 4; ++nj) {
    const int col = bcol + wc * 64 + nj * 16 + lane15;
    const float bv = bias[col];
#pragma unroll
    for (int mi = 0; mi < 4; ++mi) {
#pragma unroll
      for (int tt = 0; tt < 4; ++tt) {
        const int row = brow + wr * 64 + mi * 16 + rsub + tt;
        float v = acc[mi][nj][tt] + bv;
        if (act) v = (v > 0.f) ? (v + 1.f) : __expf(v);
        if (OUTBF16) ((short*)Cout)[(size_t)row * D_MODEL + col] = f2b(v);
        else ((float*)Cout)[(size_t)row * D_MODEL + col] = v;
      }
    }
  }
}

// ---------------- pass A: per-chunk partial sums of kf, vf ----------------
__global__ __launch_bounds__(256) void chunk_sums(
    const short* __restrict__ kf, const short* __restrict__ vf,
    float* __restrict__ ck, float* __restrict__ cv)
{
  const int gw = blockIdx.x * 4 + (threadIdx.x >> 6);  // 0..4095
  const int lane = threadIdx.x & 63;
  const int c = gw & (NCHUNK - 1);
  const int h = (gw >> 7) & (NUM_HEADS - 1);
  const int b = gw >> 11;
  const int half = lane >> 5;
  const int dpair = (lane & 31) * 2;
  const size_t base = ((size_t)(b * SEQ + c * CHUNK) * NUM_HEADS + h) * DK_DIM + dpair;

  float skx = 0.f, sky = 0.f, svx = 0.f, svy = 0.f;
#pragma unroll
  for (int i = 0; i < CHUNK / 2; ++i) {
    const size_t off = base + (size_t)(2 * i + half) * D_MODEL;
    uint32_t ku = *reinterpret_cast<const uint32_t*>(&kf[off]);
    uint32_t vu = *reinterpret_cast<const uint32_t*>(&vf[off]);
    skx += b2f((short)(ku & 0xffff)); sky += b2f((short)(ku >> 16));
    svx += b2f((short)(vu & 0xffff)); svy += b2f((short)(vu >> 16));
  }
  skx += __shfl_xor(skx, 32, 64); sky += __shfl_xor(sky, 32, 64);
  svx += __shfl_xor(svx, 32, 64); svy += __shfl_xor(svy, 32, 64);
  if (half == 0) {
    const size_t o = ((size_t)((b * NUM_HEADS + h) * NCHUNK + c)) * DK_DIM + dpair;
    f32x2 a; a.x = skx; a.y = sky;
    f32x2 bb; bb.x = svx; bb.y = svy;
    *reinterpret_cast<f32x2*>(&ck[o]) = a;
    *reinterpret_cast<f32x2*>(&cv[o]) = bb;
  }
}

// ---------------- pass B: exclusive scan over chunks (in place) + totals ------
__global__ __launch_bounds__(64) void chunk_scan(
    float* __restrict__ ck, float* __restrict__ cv, float* __restrict__ ksum)
{
  const int bh = blockIdx.x;
  const int d = threadIdx.x;
  float rk = 0.f, rv = 0.f;
#pragma unroll 8
  for (int c = 0; c < NCHUNK; ++c) {
    const size_t o = ((size_t)(bh * NCHUNK + c)) * DK_DIM + d;
    const float tk = ck[o], tv = cv[o];
    ck[o] = rk; cv[o] = rv;
    rk += tk; rv += tv;
  }
  ksum[bh * DK_DIM + d] = rk;
}

// ---------------- pass C: local cumsum + context ----------------
__global__ __launch_bounds__(256) void scan_ctx(
    const short* __restrict__ qf, const short* __restrict__ kf,
    const short* __restrict__ vf,
    const float* __restrict__ ck, const float* __restrict__ cv,
    const float* __restrict__ ksum, short* __restrict__ ctx)
{
  const int gw = blockIdx.x * 4 + (threadIdx.x >> 6);
  const int lane = threadIdx.x & 63;
  const int pg = lane >> 4;
  const int dg = lane & 15;
  const int c = gw & (NCHUNK - 1);
  const int h = (gw >> 7) & (NUM_HEADS - 1);
  const int b = gw >> 11;
  const int bh = b * NUM_HEADS + h;
  const int d4 = dg * 4;

  f32x4 krun = *reinterpret_cast<const f32x4*>(
      &ck[((size_t)(bh * NCHUNK + c)) * DK_DIM + d4]);
  f32x4 vrun = *reinterpret_cast<const f32x4*>(
      &cv[((size_t)(bh * NCHUNK + c)) * DK_DIM + d4]);
  const f32x4 kst = *reinterpret_cast<const f32x4*>(&ksum[bh * DK_DIM + d4]);

  const size_t base = ((size_t)(b * SEQ + c * CHUNK) * NUM_HEADS + h) * DK_DIM + d4;

  for (int p0 = 0; p0 < CHUNK; p0 += 4) {
    const size_t qoff = base + (size_t)(p0 + pg) * D_MODEL;
    const f32x4 q4 = b4_to_f4(*reinterpret_cast<const s16x4*>(&qf[qoff]));
    f32x4 sk, sv;
#pragma unroll
    for (int i = 0; i < 4; ++i) {
      const size_t off = base + (size_t)(p0 + i) * D_MODEL;
      krun += b4_to_f4(*reinterpret_cast<const s16x4*>(&kf[off]));
      vrun += b4_to_f4(*reinterpret_cast<const s16x4*>(&vf[off]));
      if (i == pg) { sk = krun; sv = vrun; }
    }
    float s1 = q4.x * sk.x + q4.y * sk.y + q4.z * sk.z + q4.w * sk.w;
    float s2 = q4.x * kst.x + q4.y * kst.y + q4.z * kst.z + q4.w * kst.w;
#pragma unroll
    for (int m = 1; m < 16; m <<= 1) {
      s1 += __shfl_xor(s1, m, 64);
      s2 += __shfl_xor(s2, m, 64);
    }
    const float g = s1 / (s2 + 1e-6f);
    s16x4 o;
    o.x = f2b(g * sv.x); o.y = f2b(g * sv.y);
    o.z = f2b(g * sv.z); o.w = f2b(g * sv.w);
    *reinterpret_cast<s16x4*>(&ctx[qoff]) = o;
  }
}

// ---------------- launch ----------------
extern "C" void kernel_launch(void* const* d_in, const int* in_sizes, int n_in,
                              void* d_out, int out_size, void* d_ws, size_t ws_size,
                              hipStream_t stream) {
  const float* q  = (const float*)d_in[0];
  const float* k  = (const float*)d_in[1];
  const float* v  = (const float*)d_in[2];
  const float* Wq = (const float*)d_in[3];
  const float* bq = (const float*)d_in[4];
  const float* Wk = (const float*)d_in[5];
  const float* bk = (const float*)d_in[6];
  const float* Wv = (const float*)d_in[7];
  const float* bv = (const float*)d_in[8];
  const float* Wo = (const float*)d_in[9];
  const float* bo = (const float*)d_in[10];
  float* out = (float*)d_out;

  uint8_t* p = (uint8_t*)d_ws;
  auto alloc = [&](size_t bytes) { uint8_t* r = p; p += bytes; return r; };
  short* inb = (short*)alloc((size_t)MROWS * D_MODEL * 2);
  short* qf  = (short*)alloc((size_t)MROWS * D_MODEL * 2);
  short* kf  = (short*)alloc((size_t)MROWS * D_MODEL * 2);
  short* vf  = (short*)alloc((size_t)MROWS * D_MODEL * 2);
  short* Wqb = (short*)alloc((size_t)D_MODEL * D_MODEL * 2);  // Wqb..Wob contiguous
  short* Wkb = (short*)alloc((size_t)D_MODEL * D_MODEL * 2);
  short* Wvb = (short*)alloc((size_t)D_MODEL * D_MODEL * 2);
  short* Wob = (short*)alloc((size_t)D_MODEL * D_MODEL * 2);
  float* ck   = (float*)alloc((size_t)BATCH * NUM_HEADS * NCHUNK * DK_DIM * 4);
  float* cv   = (float*)alloc((size_t)BATCH * NUM_HEADS * NCHUNK * DK_DIM * 4);
  float* ksum = (float*)alloc((size_t)BATCH * NUM_HEADS * DK_DIM * 4);
  short* ctx = inb;

  const int n4in = MROWS * D_MODEL / 4;
  const dim3 ggrid(MROWS / BM, D_MODEL / BN);   // (32, 8) = 256 blocks = 1/CU
  const int shbytes = NSLOT * SLOT_SH * (int)sizeof(short);  // 147456

  (void)hipFuncSetAttribute((const void*)gemm8<1>,
      hipFuncAttributeMaxDynamicSharedMemorySize, shbytes);
  (void)hipFuncSetAttribute((const void*)gemm8<0>,
      hipFuncAttributeMaxDynamicSharedMemorySize, shbytes);

  // weights -> bf16 (one launch)
  cvt_w4<<<dim3(D_MODEL * D_MODEL / 4 / 256, 4), 256, 0, stream>>>(Wq, Wk, Wv, Wo, Wqb);

  // projections
  cvt_f32_bf16<<<n4in / 256, 256, 0, stream>>>(q, inb, n4in);
  gemm8<1><<<ggrid, 512, shbytes, stream>>>(inb, Wqb, bq, qf, 1);
  cvt_f32_bf16<<<n4in / 256, 256, 0, stream>>>(k, inb, n4in);
  gemm8<1><<<ggrid, 512, shbytes, stream>>>(inb, Wkb, bk, kf, 1);
  cvt_f32_bf16<<<n4in / 256, 256, 0, stream>>>(v, inb, n4in);
  gemm8<1><<<ggrid, 512, shbytes, stream>>>(inb, Wvb, bv, vf, 0);

  // scan
  chunk_sums<<<BATCH * NUM_HEADS * NCHUNK / 4, 256, 0, stream>>>(kf, vf, ck, cv);
  chunk_scan<<<BATCH * NUM_HEADS, 64, 0, stream>>>(ck, cv, ksum);
  scan_ctx<<<BATCH * NUM_HEADS * NCHUNK / 4, 256, 0, stream>>>(qf, kf, vf, ck, cv, ksum, ctx);

  // output projection (f32 out)
  gemm8<0><<<ggrid, 512, shbytes, stream>>>(ctx, Wob, bo, out, 0);
}

// Round 4
// 144.254 us; speedup vs baseline: 1.4551x; 1.0716x over previous
//
#include <hip/hip_runtime.h>
#include <hip/hip_bf16.h>
#include <cstdint>
#include <cstddef>

#define D_MODEL 1024
#define NUM_HEADS 16
#define DK_DIM 64
#define BATCH 2
#define SEQ 4096
#define MROWS (BATCH*SEQ)
#define NCHUNK 128
#define CHUNK 32

// ---- 8-wave deep-pipelined GEMM geometry ----
#define BM 256
#define BN 128
#define BK 64
#define NSLOT 3
#define SLOT_SH (BM*BK + BN*BK)       // shorts per LDS slot (24576)
#define KTILES (D_MODEL/BK)           // 16

typedef __attribute__((ext_vector_type(4))) float f32x4;
typedef __attribute__((ext_vector_type(2))) float f32x2;
typedef __attribute__((ext_vector_type(8))) short bf16x8;
typedef __attribute__((ext_vector_type(4))) short s16x4;
typedef __attribute__((ext_vector_type(2))) uint32_t u32x2;
typedef __attribute__((ext_vector_type(4))) uint32_t u32x4;

__device__ __forceinline__ float b2f(short s) {
  union { uint32_t u; float f; } c; c.u = ((uint32_t)(uint16_t)s) << 16; return c.f;
}
__device__ __forceinline__ short f2b(float f) {
  union { float f; uint32_t u; } c; c.f = f;
  uint32_t u = c.u;
  u += 0x7FFFu + ((u >> 16) & 1u);
  return (short)(u >> 16);
}
__device__ __forceinline__ f32x4 b4_to_f4(s16x4 s) {
  f32x4 r;
  r.x = b2f(s.x); r.y = b2f(s.y); r.z = b2f(s.z); r.w = b2f(s.w);
  return r;
}
// packed f32x2 -> bf16x2 (RNE), gfx950 (no builtin; T12 recipe)
__device__ __forceinline__ uint32_t cvtpk(float lo, float hi) {
  uint32_t r;
  asm("v_cvt_pk_bf16_f32 %0, %1, %2" : "=v"(r) : "v"(lo), "v"(hi));
  return r;
}

// ---- 4 weight tensors in one launch; dst regions contiguous ----
__global__ __launch_bounds__(256) void cvt_w4(
    const float* __restrict__ s0, const float* __restrict__ s1,
    const float* __restrict__ s2, const float* __restrict__ s3,
    short* __restrict__ dst) {
  const int y = blockIdx.y;
  const float* s = (y == 0) ? s0 : (y == 1) ? s1 : (y == 2) ? s2 : s3;
  const int i = blockIdx.x * 256 + threadIdx.x;          // < 262144
  float4 v = reinterpret_cast<const float4*>(s)[i];
  s16x4 o;
  o.x = f2b(v.x); o.y = f2b(v.y); o.z = f2b(v.z); o.w = f2b(v.w);
  reinterpret_cast<s16x4*>(dst)[(size_t)y * (D_MODEL * D_MODEL / 4) + i] = o;
}

// ---------------- deep-pipelined bf16 GEMM: C = A @ W.T + bias ----------------
// AFP32=1: A is f32 [M][1024], converted in-register during staging (fused cvt).
// AFP32=0: A is bf16 [M][1024], staged via global_load_lds.
// W: [N][1024] bf16 row-major. 512 thr = 8 waves (4M x 2N), 64x64 out/wave.
// 3-slot rotating LDS (144KB), counted vmcnt, T2 swizzle, T5 setprio.
// MFMA args swapped (B first) so each thread owns 4 consecutive C-cols -> vector stores.
template<int AFP32, int OUTBF16>
__global__ __launch_bounds__(512, 2) void gemm8(
    const void* __restrict__ Ap, const short* __restrict__ Bw,
    const float* __restrict__ bias, void* __restrict__ Cout, int act)
{
  extern __shared__ __align__(16) short lds[];
  const int tid = threadIdx.x;
  const int wid = tid >> 6;
  const int lane = tid & 63;
  const int brow = blockIdx.x * BM;
  const int bcol = blockIdx.y * BN;
  const int wr = wid >> 1, wc = wid & 1;
  const float* __restrict__ A32 = (const float*)Ap;
  const short* __restrict__ A16 = (const short*)Ap;

  f32x4 acc[4][4];
#pragma unroll
  for (int i = 0; i < 4; ++i)
#pragma unroll
    for (int j = 0; j < 4; ++j)
#pragma unroll
      for (int t = 0; t < 4; ++t) acc[i][j][t] = 0.f;

  const int srow = lane >> 3;                 // row within 8-row wave chunk
  const int gql  = lane & 7;                  // logical granule (8 elems) of this lane
  const int sgel = (gql ^ srow) * 8;          // pre-swizzled source granule (bf16 elems)

  // ---- B staging via global_load_lds (always bf16) ----
  auto stageB = [&](int t) {
    short* sB = lds + (t % NSLOT) * SLOT_SH + BM * BK;
    const int k0 = t * BK;
#pragma unroll
    for (int i = 0; i < 2; ++i) {             // B: 128 rows, 2 rounds of 64
      const int r = i * 64 + wid * 8;
      const short* g = Bw + (size_t)(bcol + r + srow) * D_MODEL + k0 + sgel;
      __builtin_amdgcn_global_load_lds((const __attribute__((address_space(1))) void*)g,
          (__attribute__((address_space(3))) void*)(sB + r * BK), 16, 0, 0);
    }
  };
  // ---- A staging, bf16 path ----
  auto stageA16 = [&](int t) {
    short* sA = lds + (t % NSLOT) * SLOT_SH;
    const int k0 = t * BK;
#pragma unroll
    for (int i = 0; i < 4; ++i) {             // A: 256 rows, 4 rounds of 64
      const int r = i * 64 + wid * 8;
      const short* g = A16 + (size_t)(brow + r + srow) * D_MODEL + k0 + sgel;
      __builtin_amdgcn_global_load_lds((const __attribute__((address_space(1))) void*)g,
          (__attribute__((address_space(3))) void*)(sA + r * BK), 16, 0, 0);
    }
  };
  // ---- A staging, f32 path: load to regs ----
  auto loadA32 = [&](int t, float4 (&buf)[8]) {
    const int k0 = t * BK;
#pragma unroll
    for (int i = 0; i < 4; ++i) {
      const float* src = A32 + (size_t)(brow + i * 64 + wid * 8 + srow) * D_MODEL + k0 + gql * 8;
      buf[2 * i]     = *reinterpret_cast<const float4*>(src);
      buf[2 * i + 1] = *reinterpret_cast<const float4*>(src + 4);
    }
  };
  // ---- A f32->bf16 convert + swizzled ds_write ----
  auto writeA32 = [&](int t, float4 (&buf)[8]) {
    char* sA = (char*)(lds + (t % NSLOT) * SLOT_SH);
#pragma unroll
    for (int i = 0; i < 4; ++i) {
      u32x4 w;
      w.x = cvtpk(buf[2 * i].x,     buf[2 * i].y);
      w.y = cvtpk(buf[2 * i].z,     buf[2 * i].w);
      w.z = cvtpk(buf[2 * i + 1].x, buf[2 * i + 1].y);
      w.w = cvtpk(buf[2 * i + 1].z, buf[2 * i + 1].w);
      const int ebyte = (i * 64 + wid * 8 + srow) * 128 + ((gql ^ srow) * 16);
      *reinterpret_cast<u32x4*>(sA + ebyte) = w;
    }
  };

  const int lane15 = lane & 15;
  const int swz = (lane & 7) << 4;            // read-side XOR (row&7)
  const int kq = (lane >> 4) * 16;            // byte offset of lane's 8-elem k-group

  // ---- one K-tile of compute (4 phases, slot t%3) ----
  auto compute = [&](int t) {
    const char* sAb = (const char*)(lds + (t % NSLOT) * SLOT_SH);
    const char* sBb = sAb + BM * BK * 2;
    auto rdA = [&](int mi, int ks) -> bf16x8 {
      const int row = wr * 64 + mi * 16 + lane15;
      const int off = row * 128 + ((ks * 64 + kq) ^ swz);
      return *reinterpret_cast<const bf16x8*>(sAb + off);
    };
    auto rdB = [&](int nj, int ks) -> bf16x8 {
      const int row = wc * 64 + nj * 16 + lane15;
      const int off = row * 128 + ((ks * 64 + kq) ^ swz);
      return *reinterpret_cast<const bf16x8*>(sBb + off);
    };
    bf16x8 Af[2][2], Bf[2][2][2];
    // ph0: (m0, n0)
#pragma unroll
    for (int m2 = 0; m2 < 2; ++m2)
#pragma unroll
      for (int ks = 0; ks < 2; ++ks) Af[m2][ks] = rdA(m2, ks);
#pragma unroll
    for (int j2 = 0; j2 < 2; ++j2)
#pragma unroll
      for (int ks = 0; ks < 2; ++ks) Bf[0][j2][ks] = rdB(j2, ks);
    __builtin_amdgcn_s_setprio(1);
#pragma unroll
    for (int m2 = 0; m2 < 2; ++m2)
#pragma unroll
      for (int j2 = 0; j2 < 2; ++j2)
#pragma unroll
        for (int ks = 0; ks < 2; ++ks)
          acc[m2][j2] = __builtin_amdgcn_mfma_f32_16x16x32_bf16(Bf[0][j2][ks], Af[m2][ks], acc[m2][j2], 0, 0, 0);
    __builtin_amdgcn_s_setprio(0);
    __builtin_amdgcn_sched_barrier(0);
    // ph1: (m0, n1)
#pragma unroll
    for (int j2 = 0; j2 < 2; ++j2)
#pragma unroll
      for (int ks = 0; ks < 2; ++ks) Bf[1][j2][ks] = rdB(2 + j2, ks);
    __builtin_amdgcn_s_setprio(1);
#pragma unroll
    for (int m2 = 0; m2 < 2; ++m2)
#pragma unroll
      for (int j2 = 0; j2 < 2; ++j2)
#pragma unroll
        for (int ks = 0; ks < 2; ++ks)
          acc[m2][2 + j2] = __builtin_amdgcn_mfma_f32_16x16x32_bf16(Bf[1][j2][ks], Af[m2][ks], acc[m2][2 + j2], 0, 0, 0);
    __builtin_amdgcn_s_setprio(0);
    __builtin_amdgcn_sched_barrier(0);
    // ph2: (m1, n1)
#pragma unroll
    for (int m2 = 0; m2 < 2; ++m2)
#pragma unroll
      for (int ks = 0; ks < 2; ++ks) Af[m2][ks] = rdA(2 + m2, ks);
    __builtin_amdgcn_s_setprio(1);
#pragma unroll
    for (int m2 = 0; m2 < 2; ++m2)
#pragma unroll
      for (int j2 = 0; j2 < 2; ++j2)
#pragma unroll
        for (int ks = 0; ks < 2; ++ks)
          acc[2 + m2][2 + j2] = __builtin_amdgcn_mfma_f32_16x16x32_bf16(Bf[1][j2][ks], Af[m2][ks], acc[2 + m2][2 + j2], 0, 0, 0);
    __builtin_amdgcn_s_setprio(0);
    __builtin_amdgcn_sched_barrier(0);
    // ph3: (m1, n0)
    __builtin_amdgcn_s_setprio(1);
#pragma unroll
    for (int m2 = 0; m2 < 2; ++m2)
#pragma unroll
      for (int j2 = 0; j2 < 2; ++j2)
#pragma unroll
        for (int ks = 0; ks < 2; ++ks)
          acc[2 + m2][j2] = __builtin_amdgcn_mfma_f32_16x16x32_bf16(Bf[0][j2][ks], Af[m2][ks], acc[2 + m2][j2], 0, 0, 0);
    __builtin_amdgcn_s_setprio(0);
    __builtin_amdgcn_sched_barrier(0);
  };

  if constexpr (AFP32) {
    // reg-staged A pipeline: A(t+1) in regs -> ds_write pre-barrier; A(t+2) loads
    // issued pre-barrier (no LDS hazard); B(t+2) gload_lds post-barrier.
    float4 buf0[8], buf1[8];
    loadA32(0, buf0);
    asm volatile("s_waitcnt vmcnt(0)" ::: "memory");
    writeA32(0, buf0);
    loadA32(1, buf1);
    stageB(0); stageB(1);

    auto body = [&](int t, float4 (&bufW)[8], float4 (&bufL)[8]) {
      // gate: A(t+1) regs ready (leaves B(t+1)'s 2 gloads outstanding)
      if (t == KTILES - 1) { asm volatile("s_waitcnt vmcnt(0)" ::: "memory"); }
      else                 { asm volatile("s_waitcnt vmcnt(2)" ::: "memory"); }
      if (t + 1 < KTILES) writeA32(t + 1, bufW);      // slot (t+1)%3: readers done pre-barrier(t-1)
      if (t + 2 < KTILES) loadA32(t + 2, bufL);       // global->reg, no LDS hazard
      asm volatile("s_waitcnt lgkmcnt(0)" ::: "memory");  // flush ds_writes before barrier
      __builtin_amdgcn_s_barrier();
      __builtin_amdgcn_sched_barrier(0);
      if (t + 2 < KTILES) stageB(t + 2);              // slot (t+2)%3: readers done at barrier(t)
      compute(t);
    };
#pragma unroll 1
    for (int t2 = 0; t2 < KTILES; t2 += 2) {
      body(t2,     buf1, buf0);
      body(t2 + 1, buf0, buf1);
    }
  } else {
    // bf16-A pipeline (round-3 schedule): 6 gload_lds per tile, vmcnt(6)
    stageA16(0); stageB(0);
    stageA16(1); stageB(1);
#pragma unroll 1
    for (int t = 0; t < KTILES; ++t) {
      if (t == KTILES - 1) { asm volatile("s_waitcnt vmcnt(0)" ::: "memory"); }
      else                 { asm volatile("s_waitcnt vmcnt(6)" ::: "memory"); }
      __builtin_amdgcn_s_barrier();
      __builtin_amdgcn_sched_barrier(0);
      if (t + 2 < KTILES) { stageA16(t + 2); stageB(t + 2); }
      compute(t);
    }
  }

  // epilogue: swapped layout -> row(M)=lane15-based, 4 consecutive cols per store
  const int csub4 = (lane >> 4) * 4;
#pragma unroll
  for (int mi = 0; mi < 4; ++mi) {
    const int row = brow + wr * 64 + mi * 16 + lane15;
    const size_t rowbase = (size_t)row * D_MODEL;
#pragma unroll
    for (int nj = 0; nj < 4; ++nj) {
      const int col0 = bcol + wc * 64 + nj * 16 + csub4;
      const float4 bv = *reinterpret_cast<const float4*>(&bias[col0]);
      float v0 = acc[mi][nj][0] + bv.x;
      float v1 = acc[mi][nj][1] + bv.y;
      float v2 = acc[mi][nj][2] + bv.z;
      float v3 = acc[mi][nj][3] + bv.w;
      if (act) {
        v0 = (v0 > 0.f) ? (v0 + 1.f) : __expf(v0);
        v1 = (v1 > 0.f) ? (v1 + 1.f) : __expf(v1);
        v2 = (v2 > 0.f) ? (v2 + 1.f) : __expf(v2);
        v3 = (v3 > 0.f) ? (v3 + 1.f) : __expf(v3);
      }
      if (OUTBF16) {
        u32x2 w;
        w.x = cvtpk(v0, v1);
        w.y = cvtpk(v2, v3);
        *reinterpret_cast<u32x2*>(&((short*)Cout)[rowbase + col0]) = w;
      } else {
        float4 w; w.x = v0; w.y = v1; w.z = v2; w.w = v3;
        *reinterpret_cast<float4*>(&((float*)Cout)[rowbase + col0]) = w;
      }
    }
  }
}

// ---------------- pass A: per-chunk partial sums of kf, vf ----------------
__global__ __launch_bounds__(256) void chunk_sums(
    const short* __restrict__ kf, const short* __restrict__ vf,
    float* __restrict__ ck, float* __restrict__ cv)
{
  const int gw = blockIdx.x * 4 + (threadIdx.x >> 6);  // 0..4095
  const int lane = threadIdx.x & 63;
  const int c = gw & (NCHUNK - 1);
  const int h = (gw >> 7) & (NUM_HEADS - 1);
  const int b = gw >> 11;
  const int half = lane >> 5;
  const int dpair = (lane & 31) * 2;
  const size_t base = ((size_t)(b * SEQ + c * CHUNK) * NUM_HEADS + h) * DK_DIM + dpair;

  float skx = 0.f, sky = 0.f, svx = 0.f, svy = 0.f;
#pragma unroll
  for (int i = 0; i < CHUNK / 2; ++i) {
    const size_t off = base + (size_t)(2 * i + half) * D_MODEL;
    uint32_t ku = *reinterpret_cast<const uint32_t*>(&kf[off]);
    uint32_t vu = *reinterpret_cast<const uint32_t*>(&vf[off]);
    skx += b2f((short)(ku & 0xffff)); sky += b2f((short)(ku >> 16));
    svx += b2f((short)(vu & 0xffff)); svy += b2f((short)(vu >> 16));
  }
  skx += __shfl_xor(skx, 32, 64); sky += __shfl_xor(sky, 32, 64);
  svx += __shfl_xor(svx, 32, 64); svy += __shfl_xor(svy, 32, 64);
  if (half == 0) {
    const size_t o = ((size_t)((b * NUM_HEADS + h) * NCHUNK + c)) * DK_DIM + dpair;
    f32x2 a; a.x = skx; a.y = sky;
    f32x2 bb; bb.x = svx; bb.y = svy;
    *reinterpret_cast<f32x2*>(&ck[o]) = a;
    *reinterpret_cast<f32x2*>(&cv[o]) = bb;
  }
}

// ---------------- pass B: exclusive scan over chunks (in place) + totals ------
__global__ __launch_bounds__(64) void chunk_scan(
    float* __restrict__ ck, float* __restrict__ cv, float* __restrict__ ksum)
{
  const int bh = blockIdx.x;
  const int d = threadIdx.x;
  float rk = 0.f, rv = 0.f;
#pragma unroll 8
  for (int c = 0; c < NCHUNK; ++c) {
    const size_t o = ((size_t)(bh * NCHUNK + c)) * DK_DIM + d;
    const float tk = ck[o], tv = cv[o];
    ck[o] = rk; cv[o] = rv;
    rk += tk; rv += tv;
  }
  ksum[bh * DK_DIM + d] = rk;
}

// ---------------- pass C: local cumsum + context ----------------
__global__ __launch_bounds__(256) void scan_ctx(
    const short* __restrict__ qf, const short* __restrict__ kf,
    const short* __restrict__ vf,
    const float* __restrict__ ck, const float* __restrict__ cv,
    const float* __restrict__ ksum, short* __restrict__ ctx)
{
  const int gw = blockIdx.x * 4 + (threadIdx.x >> 6);
  const int lane = threadIdx.x & 63;
  const int pg = lane >> 4;
  const int dg = lane & 15;
  const int c = gw & (NCHUNK - 1);
  const int h = (gw >> 7) & (NUM_HEADS - 1);
  const int b = gw >> 11;
  const int bh = b * NUM_HEADS + h;
  const int d4 = dg * 4;

  f32x4 krun = *reinterpret_cast<const f32x4*>(
      &ck[((size_t)(bh * NCHUNK + c)) * DK_DIM + d4]);
  f32x4 vrun = *reinterpret_cast<const f32x4*>(
      &cv[((size_t)(bh * NCHUNK + c)) * DK_DIM + d4]);
  const f32x4 kst = *reinterpret_cast<const f32x4*>(&ksum[bh * DK_DIM + d4]);

  const size_t base = ((size_t)(b * SEQ + c * CHUNK) * NUM_HEADS + h) * DK_DIM + d4;

  for (int p0 = 0; p0 < CHUNK; p0 += 4) {
    const size_t qoff = base + (size_t)(p0 + pg) * D_MODEL;
    const f32x4 q4 = b4_to_f4(*reinterpret_cast<const s16x4*>(&qf[qoff]));
    f32x4 sk, sv;
#pragma unroll
    for (int i = 0; i < 4; ++i) {
      const size_t off = base + (size_t)(p0 + i) * D_MODEL;
      krun += b4_to_f4(*reinterpret_cast<const s16x4*>(&kf[off]));
      vrun += b4_to_f4(*reinterpret_cast<const s16x4*>(&vf[off]));
      if (i == pg) { sk = krun; sv = vrun; }
    }
    float s1 = q4.x * sk.x + q4.y * sk.y + q4.z * sk.z + q4.w * sk.w;
    float s2 = q4.x * kst.x + q4.y * kst.y + q4.z * kst.z + q4.w * kst.w;
#pragma unroll
    for (int m = 1; m < 16; m <<= 1) {
      s1 += __shfl_xor(s1, m, 64);
      s2 += __shfl_xor(s2, m, 64);
    }
    const float g = s1 / (s2 + 1e-6f);
    s16x4 o;
    o.x = f2b(g * sv.x); o.y = f2b(g * sv.y);
    o.z = f2b(g * sv.z); o.w = f2b(g * sv.w);
    *reinterpret_cast<s16x4*>(&ctx[qoff]) = o;
  }
}

// ---------------- launch ----------------
extern "C" void kernel_launch(void* const* d_in, const int* in_sizes, int n_in,
                              void* d_out, int out_size, void* d_ws, size_t ws_size,
                              hipStream_t stream) {
  const float* q  = (const float*)d_in[0];
  const float* k  = (const float*)d_in[1];
  const float* v  = (const float*)d_in[2];
  const float* Wq = (const float*)d_in[3];
  const float* bq = (const float*)d_in[4];
  const float* Wk = (const float*)d_in[5];
  const float* bk = (const float*)d_in[6];
  const float* Wv = (const float*)d_in[7];
  const float* bv = (const float*)d_in[8];
  const float* Wo = (const float*)d_in[9];
  const float* bo = (const float*)d_in[10];
  float* out = (float*)d_out;

  uint8_t* p = (uint8_t*)d_ws;
  auto alloc = [&](size_t bytes) { uint8_t* r = p; p += bytes; return r; };
  short* qf  = (short*)alloc((size_t)MROWS * D_MODEL * 2);
  short* kf  = (short*)alloc((size_t)MROWS * D_MODEL * 2);
  short* vf  = (short*)alloc((size_t)MROWS * D_MODEL * 2);
  short* ctx = (short*)alloc((size_t)MROWS * D_MODEL * 2);
  short* Wqb = (short*)alloc((size_t)D_MODEL * D_MODEL * 2);  // Wqb..Wob contiguous
  short* Wkb = (short*)alloc((size_t)D_MODEL * D_MODEL * 2);
  short* Wvb = (short*)alloc((size_t)D_MODEL * D_MODEL * 2);
  short* Wob = (short*)alloc((size_t)D_MODEL * D_MODEL * 2);
  float* ck   = (float*)alloc((size_t)BATCH * NUM_HEADS * NCHUNK * DK_DIM * 4);
  float* cv   = (float*)alloc((size_t)BATCH * NUM_HEADS * NCHUNK * DK_DIM * 4);
  float* ksum = (float*)alloc((size_t)BATCH * NUM_HEADS * DK_DIM * 4);

  const dim3 ggrid(MROWS / BM, D_MODEL / BN);   // (32, 8) = 256 blocks = 1/CU
  const int shbytes = NSLOT * SLOT_SH * (int)sizeof(short);  // 147456

  (void)hipFuncSetAttribute((const void*)gemm8<1, 1>,
      hipFuncAttributeMaxDynamicSharedMemorySize, shbytes);
  (void)hipFuncSetAttribute((const void*)gemm8<0, 0>,
      hipFuncAttributeMaxDynamicSharedMemorySize, shbytes);

  // weights -> bf16 (one launch)
  cvt_w4<<<dim3(D_MODEL * D_MODEL / 4 / 256, 4), 256, 0, stream>>>(Wq, Wk, Wv, Wo, Wqb);

  // projections: f32 A read + in-register cvt fused into the GEMM
  gemm8<1, 1><<<ggrid, 512, shbytes, stream>>>(q, Wqb, bq, qf, 1);
  gemm8<1, 1><<<ggrid, 512, shbytes, stream>>>(k, Wkb, bk, kf, 1);
  gemm8<1, 1><<<ggrid, 512, shbytes, stream>>>(v, Wvb, bv, vf, 0);

  // scan
  chunk_sums<<<BATCH * NUM_HEADS * NCHUNK / 4, 256, 0, stream>>>(kf, vf, ck, cv);
  chunk_scan<<<BATCH * NUM_HEADS, 64, 0, stream>>>(ck, cv, ksum);
  scan_ctx<<<BATCH * NUM_HEADS * NCHUNK / 4, 256, 0, stream>>>(qf, kf, vf, ck, cv, ksum, ctx);

  // output projection (bf16 A, f32 out)
  gemm8<0, 0><<<ggrid, 512, shbytes, stream>>>(ctx, Wob, bo, out, 0);
}

// Round 5
// 140.805 us; speedup vs baseline: 1.4908x; 1.0245x over previous
//
#include <hip/hip_runtime.h>
#include <hip/hip_bf16.h>
#include <cstdint>
#include <cstddef>

#define D_MODEL 1024
#define NUM_HEADS 16
#define DK_DIM 64
#define BATCH 2
#define SEQ 4096
#define MROWS (BATCH*SEQ)
#define NCHUNK 128
#define CHUNK 32

// ---- 8-wave deep-pipelined GEMM geometry ----
#define BM 256
#define BN 128
#define BK 64
#define NSLOT 3
#define SLOT_SH (BM*BK + BN*BK)       // shorts per LDS slot (24576)
#define KTILES (D_MODEL/BK)           // 16

typedef __attribute__((ext_vector_type(4))) float f32x4;
typedef __attribute__((ext_vector_type(2))) float f32x2;
typedef __attribute__((ext_vector_type(8))) short bf16x8;
typedef __attribute__((ext_vector_type(4))) short s16x4;
typedef __attribute__((ext_vector_type(2))) uint32_t u32x2;
typedef __attribute__((ext_vector_type(4))) uint32_t u32x4;

__device__ __forceinline__ float b2f(short s) {
  union { uint32_t u; float f; } c; c.u = ((uint32_t)(uint16_t)s) << 16; return c.f;
}
__device__ __forceinline__ short f2b(float f) {
  union { float f; uint32_t u; } c; c.f = f;
  uint32_t u = c.u;
  u += 0x7FFFu + ((u >> 16) & 1u);
  return (short)(u >> 16);
}
__device__ __forceinline__ f32x4 b4_to_f4(s16x4 s) {
  f32x4 r;
  r.x = b2f(s.x); r.y = b2f(s.y); r.z = b2f(s.z); r.w = b2f(s.w);
  return r;
}
// packed f32x2 -> bf16x2 (RNE), gfx950 (no builtin; T12 recipe)
__device__ __forceinline__ uint32_t cvtpk(float lo, float hi) {
  uint32_t r;
  asm("v_cvt_pk_bf16_f32 %0, %1, %2" : "=v"(r) : "v"(lo), "v"(hi));
  return r;
}

// ---- 4 weight tensors in one launch; dst regions contiguous ----
__global__ __launch_bounds__(256) void cvt_w4(
    const float* __restrict__ s0, const float* __restrict__ s1,
    const float* __restrict__ s2, const float* __restrict__ s3,
    short* __restrict__ dst) {
  const int y = blockIdx.y;
  const float* s = (y == 0) ? s0 : (y == 1) ? s1 : (y == 2) ? s2 : s3;
  const int i = blockIdx.x * 256 + threadIdx.x;          // < 262144
  float4 v = reinterpret_cast<const float4*>(s)[i];
  s16x4 o;
  o.x = f2b(v.x); o.y = f2b(v.y); o.z = f2b(v.z); o.w = f2b(v.w);
  reinterpret_cast<s16x4*>(dst)[(size_t)y * (D_MODEL * D_MODEL / 4) + i] = o;
}

// ---------------- deep-pipelined bf16 GEMM: C = A @ W.T + bias ----------------
// AFP32=1: A is f32 [M][1024], converted in-register during staging (fused cvt).
// AFP32=0: A is bf16 [M][1024], staged via global_load_lds.
// blockIdx.z selects (A, W, bias, C) set: W/C are z-contiguous, A/bias by pointer.
// 512 thr = 8 waves (4M x 2N), 64x64 out/wave. 3-slot rotating LDS (144KB),
// counted vmcnt, T2 swizzle. NO intra-tile fences: compiler interleaves
// ds_reads with MFMA (m97-style fine-grained lgkmcnt scheduling).
// MFMA args swapped (B first) so each thread owns 4 consecutive C-cols.
template<int AFP32, int OUTBF16>
__global__ __launch_bounds__(512, 2) void gemm8(
    const void* __restrict__ A0, const void* __restrict__ A1,
    const void* __restrict__ A2, const short* __restrict__ Wbase,
    const float* __restrict__ b0, const float* __restrict__ b1,
    const float* __restrict__ b2, void* __restrict__ Cbase, int actmask)
{
  extern __shared__ __align__(16) short lds[];
  const int tid = threadIdx.x;
  const int wid = tid >> 6;
  const int lane = tid & 63;
  const int brow = blockIdx.x * BM;
  const int bcol = blockIdx.y * BN;
  const int z = blockIdx.z;
  const int wr = wid >> 1, wc = wid & 1;

  const void* Ap = (z == 0) ? A0 : (z == 1) ? A1 : A2;
  const float* bias = (z == 0) ? b0 : (z == 1) ? b1 : b2;
  const short* Bw = Wbase + (size_t)z * D_MODEL * D_MODEL;
  const int act = (actmask >> z) & 1;
  const float* __restrict__ A32 = (const float*)Ap;
  const short* __restrict__ A16 = (const short*)Ap;

  f32x4 acc[4][4];
#pragma unroll
  for (int i = 0; i < 4; ++i)
#pragma unroll
    for (int j = 0; j < 4; ++j)
#pragma unroll
      for (int t = 0; t < 4; ++t) acc[i][j][t] = 0.f;

  const int srow = lane >> 3;                 // row within 8-row wave chunk
  const int gql  = lane & 7;                  // logical granule (8 elems) of this lane
  const int sgel = (gql ^ srow) * 8;          // pre-swizzled source granule (bf16 elems)

  // ---- B staging via global_load_lds (always bf16) ----
  auto stageB = [&](int t) {
    short* sB = lds + (t % NSLOT) * SLOT_SH + BM * BK;
    const int k0 = t * BK;
#pragma unroll
    for (int i = 0; i < 2; ++i) {             // B: 128 rows, 2 rounds of 64
      const int r = i * 64 + wid * 8;
      const short* g = Bw + (size_t)(bcol + r + srow) * D_MODEL + k0 + sgel;
      __builtin_amdgcn_global_load_lds((const __attribute__((address_space(1))) void*)g,
          (__attribute__((address_space(3))) void*)(sB + r * BK), 16, 0, 0);
    }
  };
  // ---- A staging, bf16 path ----
  auto stageA16 = [&](int t) {
    short* sA = lds + (t % NSLOT) * SLOT_SH;
    const int k0 = t * BK;
#pragma unroll
    for (int i = 0; i < 4; ++i) {             // A: 256 rows, 4 rounds of 64
      const int r = i * 64 + wid * 8;
      const short* g = A16 + (size_t)(brow + r + srow) * D_MODEL + k0 + sgel;
      __builtin_amdgcn_global_load_lds((const __attribute__((address_space(1))) void*)g,
          (__attribute__((address_space(3))) void*)(sA + r * BK), 16, 0, 0);
    }
  };
  // ---- A staging, f32 path: load to regs ----
  auto loadA32 = [&](int t, float4 (&buf)[8]) {
    const int k0 = t * BK;
#pragma unroll
    for (int i = 0; i < 4; ++i) {
      const float* src = A32 + (size_t)(brow + i * 64 + wid * 8 + srow) * D_MODEL + k0 + gql * 8;
      buf[2 * i]     = *reinterpret_cast<const float4*>(src);
      buf[2 * i + 1] = *reinterpret_cast<const float4*>(src + 4);
    }
  };
  // ---- A f32->bf16 convert + swizzled ds_write ----
  auto writeA32 = [&](int t, float4 (&buf)[8]) {
    char* sA = (char*)(lds + (t % NSLOT) * SLOT_SH);
#pragma unroll
    for (int i = 0; i < 4; ++i) {
      u32x4 w;
      w.x = cvtpk(buf[2 * i].x,     buf[2 * i].y);
      w.y = cvtpk(buf[2 * i].z,     buf[2 * i].w);
      w.z = cvtpk(buf[2 * i + 1].x, buf[2 * i + 1].y);
      w.w = cvtpk(buf[2 * i + 1].z, buf[2 * i + 1].w);
      const int ebyte = (i * 64 + wid * 8 + srow) * 128 + ((gql ^ srow) * 16);
      *reinterpret_cast<u32x4*>(sA + ebyte) = w;
    }
  };

  const int lane15 = lane & 15;
  const int swz = (lane & 7) << 4;            // read-side XOR (row&7)
  const int kq = (lane >> 4) * 16;            // byte offset of lane's 8-elem k-group

  // ---- one K-tile of compute: flat body, compiler-scheduled interleave ----
  auto compute = [&](int t) {
    const char* sAb = (const char*)(lds + (t % NSLOT) * SLOT_SH);
    const char* sBb = sAb + BM * BK * 2;
    auto rdA = [&](int mi, int ks) -> bf16x8 {
      const int row = wr * 64 + mi * 16 + lane15;
      const int off = row * 128 + ((ks * 64 + kq) ^ swz);
      return *reinterpret_cast<const bf16x8*>(sAb + off);
    };
    auto rdB = [&](int nj, int ks) -> bf16x8 {
      const int row = wc * 64 + nj * 16 + lane15;
      const int off = row * 128 + ((ks * 64 + kq) ^ swz);
      return *reinterpret_cast<const bf16x8*>(sBb + off);
    };
    bf16x8 Af[2][2], Bf[2][2][2];
    // quadrant (m0, n0)
#pragma unroll
    for (int m2 = 0; m2 < 2; ++m2)
#pragma unroll
      for (int ks = 0; ks < 2; ++ks) Af[m2][ks] = rdA(m2, ks);
#pragma unroll
    for (int j2 = 0; j2 < 2; ++j2)
#pragma unroll
      for (int ks = 0; ks < 2; ++ks) Bf[0][j2][ks] = rdB(j2, ks);
#pragma unroll
    for (int m2 = 0; m2 < 2; ++m2)
#pragma unroll
      for (int j2 = 0; j2 < 2; ++j2)
#pragma unroll
        for (int ks = 0; ks < 2; ++ks)
          acc[m2][j2] = __builtin_amdgcn_mfma_f32_16x16x32_bf16(Bf[0][j2][ks], Af[m2][ks], acc[m2][j2], 0, 0, 0);
    // quadrant (m0, n1)
#pragma unroll
    for (int j2 = 0; j2 < 2; ++j2)
#pragma unroll
      for (int ks = 0; ks < 2; ++ks) Bf[1][j2][ks] = rdB(2 + j2, ks);
#pragma unroll
    for (int m2 = 0; m2 < 2; ++m2)
#pragma unroll
      for (int j2 = 0; j2 < 2; ++j2)
#pragma unroll
        for (int ks = 0; ks < 2; ++ks)
          acc[m2][2 + j2] = __builtin_amdgcn_mfma_f32_16x16x32_bf16(Bf[1][j2][ks], Af[m2][ks], acc[m2][2 + j2], 0, 0, 0);
    // quadrant (m1, n1)
#pragma unroll
    for (int m2 = 0; m2 < 2; ++m2)
#pragma unroll
      for (int ks = 0; ks < 2; ++ks) Af[m2][ks] = rdA(2 + m2, ks);
#pragma unroll
    for (int m2 = 0; m2 < 2; ++m2)
#pragma unroll
      for (int j2 = 0; j2 < 2; ++j2)
#pragma unroll
        for (int ks = 0; ks < 2; ++ks)
          acc[2 + m2][2 + j2] = __builtin_amdgcn_mfma_f32_16x16x32_bf16(Bf[1][j2][ks], Af[m2][ks], acc[2 + m2][2 + j2], 0, 0, 0);
    // quadrant (m1, n0)
#pragma unroll
    for (int m2 = 0; m2 < 2; ++m2)
#pragma unroll
      for (int j2 = 0; j2 < 2; ++j2)
#pragma unroll
        for (int ks = 0; ks < 2; ++ks)
          acc[2 + m2][j2] = __builtin_amdgcn_mfma_f32_16x16x32_bf16(Bf[0][j2][ks], Af[m2][ks], acc[2 + m2][j2], 0, 0, 0);
  };

  if constexpr (AFP32) {
    // reg-staged A pipeline: A(t+1) regs -> ds_write pre-barrier; A(t+2) loads
    // issued pre-barrier (no LDS hazard); B(t+2) gload_lds post-barrier.
    float4 buf0[8], buf1[8];
    loadA32(0, buf0);
    asm volatile("s_waitcnt vmcnt(0)" ::: "memory");
    writeA32(0, buf0);
    loadA32(1, buf1);
    stageB(0); stageB(1);

    auto body = [&](int t, float4 (&bufW)[8], float4 (&bufL)[8]) {
      // gate: A(t+1) regs ready (leaves B(t+1)'s 2 gloads outstanding)
      if (t == KTILES - 1) { asm volatile("s_waitcnt vmcnt(0)" ::: "memory"); }
      else                 { asm volatile("s_waitcnt vmcnt(2)" ::: "memory"); }
      if (t + 1 < KTILES) writeA32(t + 1, bufW);      // slot (t+1)%3: readers done pre-barrier(t-1)
      if (t + 2 < KTILES) loadA32(t + 2, bufL);       // global->reg, no LDS hazard
      asm volatile("s_waitcnt lgkmcnt(0)" ::: "memory");  // flush ds_writes before barrier
      __builtin_amdgcn_s_barrier();
      __builtin_amdgcn_sched_barrier(0);              // fence: no hoist above barrier
      if (t + 2 < KTILES) stageB(t + 2);              // slot (t+2)%3: readers done at barrier(t)
      compute(t);
    };
#pragma unroll 1
    for (int t2 = 0; t2 < KTILES; t2 += 2) {
      body(t2,     buf1, buf0);
      body(t2 + 1, buf0, buf1);
    }
  } else {
    // bf16-A pipeline: 6 gload_lds per tile, vmcnt(6)
    stageA16(0); stageB(0);
    stageA16(1); stageB(1);
#pragma unroll 1
    for (int t = 0; t < KTILES; ++t) {
      if (t == KTILES - 1) { asm volatile("s_waitcnt vmcnt(0)" ::: "memory"); }
      else                 { asm volatile("s_waitcnt vmcnt(6)" ::: "memory"); }
      __builtin_amdgcn_s_barrier();
      __builtin_amdgcn_sched_barrier(0);
      if (t + 2 < KTILES) { stageA16(t + 2); stageB(t + 2); }
      compute(t);
    }
  }

  // epilogue: swapped layout -> row(M)=lane15-based, 4 consecutive cols per store
  const int csub4 = (lane >> 4) * 4;
#pragma unroll
  for (int mi = 0; mi < 4; ++mi) {
    const int row = brow + wr * 64 + mi * 16 + lane15;
    const size_t rowbase = (size_t)z * MROWS * D_MODEL + (size_t)row * D_MODEL;
#pragma unroll
    for (int nj = 0; nj < 4; ++nj) {
      const int col0 = bcol + wc * 64 + nj * 16 + csub4;
      const float4 bv = *reinterpret_cast<const float4*>(&bias[col0]);
      float v0 = acc[mi][nj][0] + bv.x;
      float v1 = acc[mi][nj][1] + bv.y;
      float v2 = acc[mi][nj][2] + bv.z;
      float v3 = acc[mi][nj][3] + bv.w;
      if (act) {
        v0 = (v0 > 0.f) ? (v0 + 1.f) : __expf(v0);
        v1 = (v1 > 0.f) ? (v1 + 1.f) : __expf(v1);
        v2 = (v2 > 0.f) ? (v2 + 1.f) : __expf(v2);
        v3 = (v3 > 0.f) ? (v3 + 1.f) : __expf(v3);
      }
      if (OUTBF16) {
        u32x2 w;
        w.x = cvtpk(v0, v1);
        w.y = cvtpk(v2, v3);
        *reinterpret_cast<u32x2*>(&((short*)Cbase)[rowbase + col0]) = w;
      } else {
        float4 w; w.x = v0; w.y = v1; w.z = v2; w.w = v3;
        *reinterpret_cast<float4*>(&((float*)Cbase)[rowbase + col0]) = w;
      }
    }
  }
}

// ---------------- pass A: per-chunk partial sums of kf, vf ----------------
__global__ __launch_bounds__(256) void chunk_sums(
    const short* __restrict__ kf, const short* __restrict__ vf,
    float* __restrict__ ck, float* __restrict__ cv)
{
  const int gw = blockIdx.x * 4 + (threadIdx.x >> 6);  // 0..4095
  const int lane = threadIdx.x & 63;
  const int c = gw & (NCHUNK - 1);
  const int h = (gw >> 7) & (NUM_HEADS - 1);
  const int b = gw >> 11;
  const int half = lane >> 5;
  const int dpair = (lane & 31) * 2;
  const size_t base = ((size_t)(b * SEQ + c * CHUNK) * NUM_HEADS + h) * DK_DIM + dpair;

  float skx = 0.f, sky = 0.f, svx = 0.f, svy = 0.f;
#pragma unroll
  for (int i = 0; i < CHUNK / 2; ++i) {
    const size_t off = base + (size_t)(2 * i + half) * D_MODEL;
    uint32_t ku = *reinterpret_cast<const uint32_t*>(&kf[off]);
    uint32_t vu = *reinterpret_cast<const uint32_t*>(&vf[off]);
    skx += b2f((short)(ku & 0xffff)); sky += b2f((short)(ku >> 16));
    svx += b2f((short)(vu & 0xffff)); svy += b2f((short)(vu >> 16));
  }
  skx += __shfl_xor(skx, 32, 64); sky += __shfl_xor(sky, 32, 64);
  svx += __shfl_xor(svx, 32, 64); svy += __shfl_xor(svy, 32, 64);
  if (half == 0) {
    const size_t o = ((size_t)((b * NUM_HEADS + h) * NCHUNK + c)) * DK_DIM + dpair;
    f32x2 a; a.x = skx; a.y = sky;
    f32x2 bb; bb.x = svx; bb.y = svy;
    *reinterpret_cast<f32x2*>(&ck[o]) = a;
    *reinterpret_cast<f32x2*>(&cv[o]) = bb;
  }
}

// ---------------- pass B: exclusive scan over chunks (in place) + totals ------
__global__ __launch_bounds__(64) void chunk_scan(
    float* __restrict__ ck, float* __restrict__ cv, float* __restrict__ ksum)
{
  const int bh = blockIdx.x;
  const int d = threadIdx.x;
  float rk = 0.f, rv = 0.f;
#pragma unroll 8
  for (int c = 0; c < NCHUNK; ++c) {
    const size_t o = ((size_t)(bh * NCHUNK + c)) * DK_DIM + d;
    const float tk = ck[o], tv = cv[o];
    ck[o] = rk; cv[o] = rv;
    rk += tk; rv += tv;
  }
  ksum[bh * DK_DIM + d] = rk;
}

// ---------------- pass C: local cumsum + context ----------------
__global__ __launch_bounds__(256) void scan_ctx(
    const short* __restrict__ qf, const short* __restrict__ kf,
    const short* __restrict__ vf,
    const float* __restrict__ ck, const float* __restrict__ cv,
    const float* __restrict__ ksum, short* __restrict__ ctx)
{
  const int gw = blockIdx.x * 4 + (threadIdx.x >> 6);
  const int lane = threadIdx.x & 63;
  const int pg = lane >> 4;
  const int dg = lane & 15;
  const int c = gw & (NCHUNK - 1);
  const int h = (gw >> 7) & (NUM_HEADS - 1);
  const int b = gw >> 11;
  const int bh = b * NUM_HEADS + h;
  const int d4 = dg * 4;

  f32x4 krun = *reinterpret_cast<const f32x4*>(
      &ck[((size_t)(bh * NCHUNK + c)) * DK_DIM + d4]);
  f32x4 vrun = *reinterpret_cast<const f32x4*>(
      &cv[((size_t)(bh * NCHUNK + c)) * DK_DIM + d4]);
  const f32x4 kst = *reinterpret_cast<const f32x4*>(&ksum[bh * DK_DIM + d4]);

  const size_t base = ((size_t)(b * SEQ + c * CHUNK) * NUM_HEADS + h) * DK_DIM + d4;

  for (int p0 = 0; p0 < CHUNK; p0 += 4) {
    const size_t qoff = base + (size_t)(p0 + pg) * D_MODEL;
    const f32x4 q4 = b4_to_f4(*reinterpret_cast<const s16x4*>(&qf[qoff]));
    f32x4 sk, sv;
#pragma unroll
    for (int i = 0; i < 4; ++i) {
      const size_t off = base + (size_t)(p0 + i) * D_MODEL;
      krun += b4_to_f4(*reinterpret_cast<const s16x4*>(&kf[off]));
      vrun += b4_to_f4(*reinterpret_cast<const s16x4*>(&vf[off]));
      if (i == pg) { sk = krun; sv = vrun; }
    }
    float s1 = q4.x * sk.x + q4.y * sk.y + q4.z * sk.z + q4.w * sk.w;
    float s2 = q4.x * kst.x + q4.y * kst.y + q4.z * kst.z + q4.w * kst.w;
#pragma unroll
    for (int m = 1; m < 16; m <<= 1) {
      s1 += __shfl_xor(s1, m, 64);
      s2 += __shfl_xor(s2, m, 64);
    }
    const float g = s1 / (s2 + 1e-6f);
    s16x4 o;
    o.x = f2b(g * sv.x); o.y = f2b(g * sv.y);
    o.z = f2b(g * sv.z); o.w = f2b(g * sv.w);
    *reinterpret_cast<s16x4*>(&ctx[qoff]) = o;
  }
}

// ---------------- launch ----------------
extern "C" void kernel_launch(void* const* d_in, const int* in_sizes, int n_in,
                              void* d_out, int out_size, void* d_ws, size_t ws_size,
                              hipStream_t stream) {
  const float* q  = (const float*)d_in[0];
  const float* k  = (const float*)d_in[1];
  const float* v  = (const float*)d_in[2];
  const float* Wq = (const float*)d_in[3];
  const float* bq = (const float*)d_in[4];
  const float* Wk = (const float*)d_in[5];
  const float* bk = (const float*)d_in[6];
  const float* Wv = (const float*)d_in[7];
  const float* bv = (const float*)d_in[8];
  const float* Wo = (const float*)d_in[9];
  const float* bo = (const float*)d_in[10];
  float* out = (float*)d_out;

  uint8_t* p = (uint8_t*)d_ws;
  auto alloc = [&](size_t bytes) { uint8_t* r = p; p += bytes; return r; };
  short* qf  = (short*)alloc((size_t)MROWS * D_MODEL * 2);   // qf,kf,vf contiguous
  short* kf  = (short*)alloc((size_t)MROWS * D_MODEL * 2);
  short* vf  = (short*)alloc((size_t)MROWS * D_MODEL * 2);
  short* ctx = (short*)alloc((size_t)MROWS * D_MODEL * 2);
  short* Wqb = (short*)alloc((size_t)D_MODEL * D_MODEL * 2);  // Wqb..Wob contiguous
  short* Wkb = (short*)alloc((size_t)D_MODEL * D_MODEL * 2);
  short* Wvb = (short*)alloc((size_t)D_MODEL * D_MODEL * 2);
  short* Wob = (short*)alloc((size_t)D_MODEL * D_MODEL * 2);
  float* ck   = (float*)alloc((size_t)BATCH * NUM_HEADS * NCHUNK * DK_DIM * 4);
  float* cv   = (float*)alloc((size_t)BATCH * NUM_HEADS * NCHUNK * DK_DIM * 4);
  float* ksum = (float*)alloc((size_t)BATCH * NUM_HEADS * DK_DIM * 4);
  (void)Wkb; (void)Wvb;

  const dim3 gproj(MROWS / BM, D_MODEL / BN, 3);   // (32, 8, 3)
  const dim3 gout (MROWS / BM, D_MODEL / BN, 1);
  const int shbytes = NSLOT * SLOT_SH * (int)sizeof(short);  // 147456

  (void)hipFuncSetAttribute((const void*)gemm8<1, 1>,
      hipFuncAttributeMaxDynamicSharedMemorySize, shbytes);
  (void)hipFuncSetAttribute((const void*)gemm8<0, 0>,
      hipFuncAttributeMaxDynamicSharedMemorySize, shbytes);

  // weights -> bf16 (one launch)
  cvt_w4<<<dim3(D_MODEL * D_MODEL / 4 / 256, 4), 256, 0, stream>>>(Wq, Wk, Wv, Wo, Wqb);

  // all 3 projections in ONE launch (z selects input/weights/bias/output);
  // act on z=0 (q) and z=1 (k) only -> mask 0b011
  gemm8<1, 1><<<gproj, 512, shbytes, stream>>>(q, k, v, Wqb, bq, bk, bv, qf, 0x3);

  // scan
  chunk_sums<<<BATCH * NUM_HEADS * NCHUNK / 4, 256, 0, stream>>>(kf, vf, ck, cv);
  chunk_scan<<<BATCH * NUM_HEADS, 64, 0, stream>>>(ck, cv, ksum);
  scan_ctx<<<BATCH * NUM_HEADS * NCHUNK / 4, 256, 0, stream>>>(qf, kf, vf, ck, cv, ksum, ctx);

  // output projection (bf16 A, f32 out)
  gemm8<0, 0><<<gout, 512, shbytes, stream>>>(ctx, ctx, ctx, Wob, bo, bo, bo, out, 0);
}